// Round 3
// baseline (115.929 us; speedup 1.0000x reference)
//
#include <hip/hip_runtime.h>

// Median filter 1D, k=9, replicate padding. x: [2048 rows, L=8192] fp32.
// No-LDS streaming version: each thread computes 8 consecutive outputs from
// 16 contiguous inputs loaded as 4 aligned float4 (x[col0-4 .. col0+11]).
// Neighbor overlap between threads is served by L1/L2; HBM traffic stays at
// the 128 MiB minimum. Replicate padding = splat of the row-edge element
// (window positions <0 all clamp to x[0]; >=L all clamp to x[L-1]).

#define BLOCK 256
#define OPT 8                 // outputs per thread
#define TILE (BLOCK * OPT)    // 2048 outputs per block

__device__ __forceinline__ float med3(float a, float b, float c) {
    return __builtin_amdgcn_fmed3f(a, b, c);     // v_med3_f32
}
__device__ __forceinline__ float min3(float a, float b, float c) {
    return fminf(fminf(a, b), c);                // v_min3_f32
}
__device__ __forceinline__ float max3(float a, float b, float c) {
    return fmaxf(fmaxf(a, b), c);                // v_max3_f32
}

// Exact median of 9 in 13 ops.
__device__ __forceinline__ float med9(float p0, float p1, float p2,
                                      float p3, float p4, float p5,
                                      float p6, float p7, float p8) {
    float l0 = min3(p0, p1, p2), m0 = med3(p0, p1, p2), h0 = max3(p0, p1, p2);
    float l1 = min3(p3, p4, p5), m1 = med3(p3, p4, p5), h1 = max3(p3, p4, p5);
    float l2 = min3(p6, p7, p8), m2 = med3(p6, p7, p8), h2 = max3(p6, p7, p8);
    return med3(max3(l0, l1, l2), med3(m0, m1, m2), min3(h0, h1, h2));
}

__global__ __launch_bounds__(BLOCK) void median9_kernel(
    const float* __restrict__ x, float* __restrict__ out, int L, int tilesPerRow) {
    const int tid = threadIdx.x;
    const int row = blockIdx.x / tilesPerRow;
    const int col0 = (blockIdx.x % tilesPerRow) * TILE + tid * OPT;  // [0, L-8]
    const float* p = x + (long long)row * L + col0;

    // Own 8 elements: two aligned float4 loads (col0 is 32B-aligned).
    float4 A4 = ((const float4*)p)[0];
    float4 B4 = ((const float4*)p)[1];

    // Left halo x[col0-4 .. col0-1]: replicate-pad splats x[0] at the row start.
    float4 L4;
    if (col0 == 0) {
        L4 = make_float4(A4.x, A4.x, A4.x, A4.x);
    } else {
        L4 = *(const float4*)(p - 4);
    }
    // Right halo x[col0+8 .. col0+11]: splat x[L-1] at the row end.
    float4 R4;
    if (col0 + OPT == L) {
        R4 = make_float4(B4.w, B4.w, B4.w, B4.w);
    } else {
        R4 = *(const float4*)(p + 8);
    }

    // s0..s15 = x[col0-4 .. col0+11]; output j's window = s[j..j+8].
    float s0 = L4.x, s1 = L4.y, s2 = L4.z, s3 = L4.w;
    float s4 = A4.x, s5 = A4.y, s6 = A4.z, s7 = A4.w;
    float s8 = B4.x, s9 = B4.y, s10 = B4.z, s11 = B4.w;
    float s12 = R4.x, s13 = R4.y, s14 = R4.z, s15 = R4.w;

    float4 r0, r1;
    r0.x = med9(s0, s1, s2, s3, s4, s5, s6, s7, s8);
    r0.y = med9(s1, s2, s3, s4, s5, s6, s7, s8, s9);
    r0.z = med9(s2, s3, s4, s5, s6, s7, s8, s9, s10);
    r0.w = med9(s3, s4, s5, s6, s7, s8, s9, s10, s11);
    r1.x = med9(s4, s5, s6, s7, s8, s9, s10, s11, s12);
    r1.y = med9(s5, s6, s7, s8, s9, s10, s11, s12, s13);
    r1.z = med9(s6, s7, s8, s9, s10, s11, s12, s13, s14);
    r1.w = med9(s7, s8, s9, s10, s11, s12, s13, s14, s15);

    float* o = out + (long long)row * L + col0;
    ((float4*)o)[0] = r0;
    ((float4*)o)[1] = r1;
}

extern "C" void kernel_launch(void* const* d_in, const int* in_sizes, int n_in,
                              void* d_out, int out_size, void* d_ws, size_t ws_size,
                              hipStream_t stream) {
    const float* x = (const float*)d_in[0];
    float* out = (float*)d_out;
    const int L = 8192;                 // static per the reference setup
    const int rows = in_sizes[0] / L;   // 32*64 = 2048
    const int tilesPerRow = L / TILE;   // 4
    const int nblocks = rows * tilesPerRow;   // 8192
    median9_kernel<<<nblocks, BLOCK, 0, stream>>>(x, out, L, tilesPerRow);
}